// Round 3
// baseline (20433.914 us; speedup 1.0000x reference)
//
#include <hip/hip_runtime.h>
#include <math.h>

// Problem constants
// V=10000, E=256, H=256, D=256, A=256, B=128, S=64
// 3H = 768, 2H = 512, feat = [h_new(256), w(512), e(256)] = 1024

__device__ __forceinline__ float dot4(const float4 a, const float4 b) {
    return fmaf(a.x, b.x, fmaf(a.y, b.y, fmaf(a.z, b.z, a.w * b.w)));
}

// ---------------------------------------------------------------------------
// Fused encoder: 128 blocks x 512 threads. Block = 2 batches x 1 dir, thread =
// (batch-sel, dim). Loops all 64 timesteps with __syncthreads only (recurrence
// is per-batch independent). Embedding gather is inlined. Per-thread k-loop is
// a verbatim copy of the round-2 accumulation order -> bit-identical h.
__global__ __launch_bounds__(512) void enc_loop_kernel(
    const int* __restrict__ inp, const float* __restrict__ table,
    const float* __restrict__ Wih_f, const float* __restrict__ Whh_f,
    const float* __restrict__ bih_f, const float* __restrict__ bhh_f,
    const float* __restrict__ Wih_b, const float* __restrict__ Whh_b,
    const float* __restrict__ bih_b, const float* __restrict__ bhh_b,
    float* __restrict__ hf, float* __restrict__ hb,
    float* __restrict__ enc_out)
{
    const int bid = blockIdx.x;            // 0..127
    const int dir = bid >> 6;              // 0..1
    const int b0  = (bid & 63) * 2;
    const float* Wih = dir ? Wih_b : Wih_f;
    const float* Whh = dir ? Whh_b : Whh_f;
    const float* bih = dir ? bih_b : bih_f;
    const float* bhh = dir ? bhh_b : bhh_f;

    const int tid  = threadIdx.x;
    const int d    = tid & 255;
    const int bsel = tid >> 8;             // 0..1
    const int b    = b0 + bsel;

    __shared__ __align__(16) float xs[2][256];
    __shared__ __align__(16) float hs[2][2][256];   // [buf][bsel][d]

    hs[0][bsel][d] = 0.f;

    const float4* wr_i = (const float4*)(Wih + (size_t)d * 256);
    const float4* wz_i = (const float4*)(Wih + (size_t)(256 + d) * 256);
    const float4* wn_i = (const float4*)(Wih + (size_t)(512 + d) * 256);
    const float4* wr_h = (const float4*)(Whh + (size_t)d * 256);
    const float4* wz_h = (const float4*)(Whh + (size_t)(256 + d) * 256);
    const float4* wn_h = (const float4*)(Whh + (size_t)(512 + d) * 256);

    const float br = bih[d] + bhh[d];
    const float bz = bih[256 + d] + bhh[256 + d];
    const float bnx = bih[512 + d];
    const float bnh = bhh[512 + d];

    float hn = 0.f;
    int cur = 0;
    for (int step = 0; step < 64; ++step) {
        const int t = dir ? (63 - step) : step;
        __syncthreads();
        {
            int tok = inp[(b * 64 + t) * 2];
            float msk = (float)inp[(b * 64 + t) * 2 + 1];
            xs[bsel][d] = table[(size_t)tok * 256 + d] * msk;
        }
        __syncthreads();

        const float4* x4 = (const float4*)xs[bsel];
        const float4* h4 = (const float4*)hs[cur][bsel];
        float rs = 0.f, zs = 0.f, nx = 0.f, nh = 0.f;
        for (int k = 0; k < 64; ++k) {
            float4 xv = x4[k];
            float4 hv = h4[k];
            rs += dot4(xv, wr_i[k]) + dot4(hv, wr_h[k]);
            zs += dot4(xv, wz_i[k]) + dot4(hv, wz_h[k]);
            nx += dot4(xv, wn_i[k]);
            nh += dot4(hv, wn_h[k]);
        }
        rs += br;
        zs += bz;
        nx += bnx;
        nh += bnh;

        float r = 1.0f / (1.0f + expf(-rs));
        float z = 1.0f / (1.0f + expf(-zs));
        float n = tanhf(nx + r * nh);
        float hprev = hs[cur][bsel][d];
        hn = (1.0f - z) * n + z * hprev;

        hs[cur ^ 1][bsel][d] = hn;
        enc_out[(b * 64 + t) * 512 + dir * 256 + d] = hn;
        cur ^= 1;
    }
    (dir ? hb : hf)[b * 256 + d] = hn;
}

// ---------------------------------------------------------------------------
// hidden = tanh([f_h, b_h] @ enc_fc_W.T + b)   (grid 128, block 256)
__global__ __launch_bounds__(256) void enc_fc_kernel(
    const float* __restrict__ hf, const float* __restrict__ hb,
    const float* __restrict__ W, const float* __restrict__ bias,
    float* __restrict__ hdec0)
{
    int b = blockIdx.x, tid = threadIdx.x;
    __shared__ __align__(16) float xs[512];
    xs[tid] = hf[b * 256 + tid];
    xs[256 + tid] = hb[b * 256 + tid];
    __syncthreads();
    const float4* w4 = (const float4*)(W + (size_t)tid * 512);
    const float4* x4 = (const float4*)xs;
    float s = 0.f;
    for (int k = 0; k < 128; ++k) s += dot4(x4[k], w4[k]);
    hdec0[b * 256 + tid] = tanhf(s + bias[tid]);
}

// ---------------------------------------------------------------------------
// Generic C[M,N] = A[M,K] @ W[N,K]^T + bias.  64x64 tile, 4x4 micro-tile,
// BK=64, register-double-buffered staging. Used for the one-time enc_att GEMM.
#define GP 68
__global__ __launch_bounds__(256) void gemm2_kernel(
    const float* __restrict__ Amat, int lda,
    const float* __restrict__ Wmat, int ldw,
    const float* __restrict__ bias,
    float* __restrict__ C, long ldc,
    int N, int K)
{
    const int tid = threadIdx.x;
    const int tn = tid & 15;
    const int tm = tid >> 4;
    const long m0 = (long)blockIdx.y * 64;
    const int n0 = blockIdx.x * 64;
    __shared__ __align__(16) float As[64][GP];
    __shared__ __align__(16) float Ws[64][GP];

    const float* Abase = Amat + (m0 + tm) * lda + tn * 4;
    float4 ar[4], wr[4];
    float acc[4][4] = {};

    {
#pragma unroll
        for (int q = 0; q < 4; ++q)
            ar[q] = *(const float4*)(Abase + (long)16 * q * lda);
#pragma unroll
        for (int q = 0; q < 4; ++q) {
            int n = n0 + tm + 16 * q;
            wr[q] = (n < N) ? *(const float4*)(Wmat + (long)n * ldw + tn * 4)
                            : make_float4(0.f, 0.f, 0.f, 0.f);
        }
    }

    int k0 = 0;
    while (true) {
#pragma unroll
        for (int q = 0; q < 4; ++q) {
            *(float4*)&As[tm + 16 * q][tn * 4] = ar[q];
            *(float4*)&Ws[tm + 16 * q][tn * 4] = wr[q];
        }
        __syncthreads();

        const int kn = k0 + 64;
        if (kn < K) {
#pragma unroll
            for (int q = 0; q < 4; ++q)
                ar[q] = *(const float4*)(Abase + (long)16 * q * lda + kn);
#pragma unroll
            for (int q = 0; q < 4; ++q) {
                int n = n0 + tm + 16 * q;
                wr[q] = (n < N) ? *(const float4*)(Wmat + (long)n * ldw + tn * 4 + kn)
                                : make_float4(0.f, 0.f, 0.f, 0.f);
            }
        }

#pragma unroll
        for (int kk = 0; kk < 64; kk += 4) {
            float4 av[4], wv[4];
#pragma unroll
            for (int i = 0; i < 4; ++i) av[i] = *(const float4*)&As[tm + 16 * i][kk];
#pragma unroll
            for (int j = 0; j < 4; ++j) wv[j] = *(const float4*)&Ws[tn + 16 * j][kk];
#pragma unroll
            for (int i = 0; i < 4; ++i)
#pragma unroll
                for (int j = 0; j < 4; ++j)
                    acc[i][j] += dot4(av[i], wv[j]);
        }

        if (kn >= K) break;
        __syncthreads();
        k0 = kn;
    }

#pragma unroll
    for (int i = 0; i < 4; ++i) {
        long m = m0 + tm + 16 * i;
#pragma unroll
        for (int j = 0; j < 4; ++j) {
            int n = n0 + tn + 16 * j;
            if (n < N) C[m * ldc + n] = acc[i][j] + bias[n];
        }
    }
}

// ---------------------------------------------------------------------------
// Attention phase for one decoder step, one batch b. Writes w into feat_tgt.
__device__ __forceinline__ void attn_phase(
    int b, const float* __restrict__ hprev, const float* __restrict__ attn_W,
    const float* __restrict__ enc_att, const float* __restrict__ enc_out,
    float* __restrict__ feat_tgt,
    float* __restrict__ hsh, float* __restrict__ hE,
    float* __restrict__ part, float* __restrict__ aw)
{
    const int tid = threadIdx.x;
    hsh[tid] = hprev[b * 256 + tid];
    __syncthreads();
    {
        const float4* w4 = (const float4*)(attn_W + (size_t)tid * 768);
        const float4* h4 = (const float4*)hsh;
        float s = 0.f;
        for (int k = 0; k < 64; ++k) s += dot4(h4[k], w4[k]);
        hE[tid] = s;
    }
    __syncthreads();
    {
        const int si = tid & 63, g = tid >> 6;
        const float* ea = enc_att + ((size_t)b * 64 + si) * 256 + g * 64;
        const float* he = hE + g * 64;
        float p = 0.f;
        for (int a = 0; a < 64; ++a) p += tanhf(he[a] + ea[a]);
        part[tid] = p;
    }
    __syncthreads();
    if (tid < 64) {
        float sc = part[tid] + part[64 + tid] + part[128 + tid] + part[192 + tid];
        float m = sc;
        for (int off = 32; off; off >>= 1) m = fmaxf(m, __shfl_xor(m, off));
        float ex = expf(sc - m);
        float sum = ex;
        for (int off = 32; off; off >>= 1) sum += __shfl_xor(sum, off);
        aw[tid] = ex / sum;
    }
    __syncthreads();
    {
        float w0 = 0.f, w1 = 0.f;
        for (int s2 = 0; s2 < 64; ++s2) {
            float as = aw[s2];
            const float* eo = enc_out + ((size_t)b * 64 + s2) * 512;
            w0 = fmaf(as, eo[tid], w0);
            w1 = fmaf(as, eo[256 + tid], w1);
        }
        feat_tgt[b * 1024 + 256 + tid] = w0;
        feat_tgt[b * 1024 + 512 + tid] = w1;
    }
}

// Standalone attn (decoder prologue, t=1).
__global__ __launch_bounds__(256) void attn_kernel(
    const float* __restrict__ hprev, const float* __restrict__ attn_W,
    const float* __restrict__ enc_att, const float* __restrict__ enc_out,
    float* __restrict__ feat_tgt)
{
    __shared__ __align__(16) float hsh[256];
    __shared__ __align__(16) float hE[256];
    __shared__ __align__(16) float part[256];
    __shared__ __align__(16) float aw[64];
    attn_phase(blockIdx.x, hprev, attn_W, enc_att, enc_out, feat_tgt, hsh, hE, part, aw);
}

// ---------------------------------------------------------------------------
// Decoder GRU step. Reads the argmax winner from slots (packed u64, or tok=0
// when slots_read==null for t=1), gathers the embedding row (bit-identical to
// the old feat.e path), stores it to fb.e for the following GEMM, and resets
// the slot buffer that this step's GEMM will atomicMax into.
__global__ __launch_bounds__(256) void dec_gru_kernel(
    const float* __restrict__ emb_tab, float* __restrict__ fb,
    const float* __restrict__ hin,
    const unsigned long long* __restrict__ slots_read,
    unsigned long long* __restrict__ slots_reset,
    const float* __restrict__ Wih, const float* __restrict__ Whh,
    const float* __restrict__ bih, const float* __restrict__ bhh,
    float* __restrict__ hout)
{
    const int tid = threadIdx.x;
    const int dl = tid & 31, bsub = tid >> 5;
    const int d0 = (blockIdx.x & 7) * 32, b0 = (blockIdx.x >> 3) * 8;
    const int d = d0 + dl, b = b0 + bsub;

    if (tid == 0) slots_reset[blockIdx.x] = 0ull;

    __shared__ __align__(16) float rin[8][768];
    __shared__ __align__(16) float hsh[8][256];

    const bool ewrite = ((blockIdx.x & 7) == 0);
    for (int i = tid; i < 2048; i += 256) {           // e -> rin[:,0:256]
        int bl = i >> 8, k = i & 255;
        int tk = 0;
        if (slots_read) {
            unsigned long long s = slots_read[b0 + bl];
            tk = (int)(~((unsigned int)(s & 0xFFFFFFFFull)));
        }
        float v = emb_tab[(size_t)tk * 256 + k];
        rin[bl][k] = v;
        if (ewrite) fb[(b0 + bl) * 1024 + 768 + k] = v;
    }
    for (int i = tid; i < 4096; i += 256) {           // w -> rin[:,256:768]
        int bl = i >> 9, k = i & 511;
        rin[bl][256 + k] = fb[(b0 + bl) * 1024 + 256 + k];
    }
    for (int i = tid; i < 2048; i += 256) {
        int bl = i >> 8, k = i & 255;
        hsh[bl][k] = hin[(b0 + bl) * 256 + k];
    }
    __syncthreads();

    const float4* xv4 = (const float4*)rin[bsub];
    const float4* hv4 = (const float4*)hsh[bsub];
    const float4* Wr = (const float4*)(Wih + (size_t)d * 768);
    const float4* Wz = (const float4*)(Wih + (size_t)(256 + d) * 768);
    const float4* Wn = (const float4*)(Wih + (size_t)(512 + d) * 768);
    const float4* Ur = (const float4*)(Whh + (size_t)d * 256);
    const float4* Uz = (const float4*)(Whh + (size_t)(256 + d) * 256);
    const float4* Un = (const float4*)(Whh + (size_t)(512 + d) * 256);

    float rs = 0.f, zs = 0.f, nx = 0.f, nh = 0.f;
    for (int k = 0; k < 192; ++k) {
        float4 xv = xv4[k];
        rs += dot4(xv, Wr[k]);
        zs += dot4(xv, Wz[k]);
        nx += dot4(xv, Wn[k]);
    }
    for (int k = 0; k < 64; ++k) {
        float4 hv = hv4[k];
        rs += dot4(hv, Ur[k]);
        zs += dot4(hv, Uz[k]);
        nh += dot4(hv, Un[k]);
    }
    rs += bih[d] + bhh[d];
    zs += bih[256 + d] + bhh[256 + d];
    nx += bih[512 + d];
    nh += bhh[512 + d];

    float r = 1.0f / (1.0f + expf(-rs));
    float z = 1.0f / (1.0f + expf(-zs));
    float n = tanhf(nx + r * nh);
    float hprev = hsh[bsub][d];
    float hn = (1.0f - z) * n + z * hprev;

    hout[b * 256 + d] = hn;
    fb[b * 1024 + d] = hn;
}

// ---------------------------------------------------------------------------
// Mega decoder kernel (378 blocks):
//   blocks 0..249  : out-projection GEMM tile (64x80, identical accumulation
//                    order -> bit-identical logits) + fused first-max argmax
//                    via per-row atomicMax of packed (ordered-value, ~index).
//   blocks 250..377: attention for the NEXT step (reads hcur, writes fnext.w).
__global__ __launch_bounds__(256) void mega_kernel(
    const float* __restrict__ fb, const float* __restrict__ Wmat,
    const float* __restrict__ bias, float* __restrict__ C,
    unsigned long long* __restrict__ slots_write,
    float* __restrict__ fnext,
    const float* __restrict__ hcur, const float* __restrict__ attn_W,
    const float* __restrict__ enc_att, const float* __restrict__ enc_out)
{
    __shared__ __align__(16) float As[64][GP];
    __shared__ __align__(16) float Ws[80][GP];
    __shared__ __align__(16) unsigned long long keys[64][16];
    __shared__ __align__(16) float a0[256];
    __shared__ __align__(16) float a1[256];
    __shared__ __align__(16) float a2[256];
    __shared__ __align__(16) float a3[64];

    const int bid = blockIdx.x;
    if (bid >= 250) {
        attn_phase(bid - 250, hcur, attn_W, enc_att, enc_out, fnext, a0, a1, a2, a3);
        return;
    }

    const int tid = threadIdx.x;
    const int tn = tid & 15;
    const int tm = tid >> 4;
    const long m0 = (long)(bid & 1) * 64;
    const int n0 = (bid >> 1) * 80;

    const float* Abase = fb + (m0 + tm) * 1024 + tn * 4;
    const float* Wbase = Wmat + (long)(n0 + tm) * 1024 + tn * 4;
    float4 ar[4], wr[5];
    float acc[4][5] = {};

    {
#pragma unroll
        for (int q = 0; q < 4; ++q)
            ar[q] = *(const float4*)(Abase + (long)16 * q * 1024);
#pragma unroll
        for (int q = 0; q < 5; ++q)
            wr[q] = *(const float4*)(Wbase + (long)16 * q * 1024);
    }

    int k0 = 0;
    while (true) {
#pragma unroll
        for (int q = 0; q < 4; ++q)
            *(float4*)&As[tm + 16 * q][tn * 4] = ar[q];
#pragma unroll
        for (int q = 0; q < 5; ++q)
            *(float4*)&Ws[tm + 16 * q][tn * 4] = wr[q];
        __syncthreads();

        const int kn = k0 + 64;
        if (kn < 1024) {
#pragma unroll
            for (int q = 0; q < 4; ++q)
                ar[q] = *(const float4*)(Abase + (long)16 * q * 1024 + kn);
#pragma unroll
            for (int q = 0; q < 5; ++q)
                wr[q] = *(const float4*)(Wbase + (long)16 * q * 1024 + kn);
        }

#pragma unroll
        for (int kk = 0; kk < 64; kk += 4) {
            float4 av[4], wv[5];
#pragma unroll
            for (int i = 0; i < 4; ++i) av[i] = *(const float4*)&As[tm + 16 * i][kk];
#pragma unroll
            for (int j = 0; j < 5; ++j) wv[j] = *(const float4*)&Ws[tn + 16 * j][kk];
#pragma unroll
            for (int i = 0; i < 4; ++i)
#pragma unroll
                for (int j = 0; j < 5; ++j)
                    acc[i][j] += dot4(av[i], wv[j]);
        }

        if (kn >= 1024) break;
        __syncthreads();
        k0 = kn;
    }

    // Store logits (identical values) and build first-max keys.
#pragma unroll
    for (int i = 0; i < 4; ++i) {
        long m = m0 + tm + 16 * i;
        unsigned long long best = 0ull;
#pragma unroll
        for (int j = 0; j < 5; ++j) {
            int n = n0 + tn + 16 * j;
            float v = acc[i][j] + bias[n];
            C[m * 640000 + n] = v;
            unsigned int bits = __float_as_uint(v);
            unsigned int ov = (bits & 0x80000000u) ? ~bits : (bits | 0x80000000u);
            unsigned long long key =
                ((unsigned long long)ov << 32) | (unsigned int)(~(unsigned int)n);
            if (key > best) best = key;
        }
        keys[tm + 16 * i][tn] = best;
    }
    __syncthreads();
    if (tid < 64) {
        unsigned long long best = keys[tid][0];
#pragma unroll
        for (int q = 1; q < 16; ++q) {
            unsigned long long k2 = keys[tid][q];
            if (k2 > best) best = k2;
        }
        atomicMax(&slots_write[m0 + tid], best);
    }
}

// ---------------------------------------------------------------------------
// In-place log_softmax over each row of d_out (8192 x 10000).
__global__ __launch_bounds__(256) void logsoftmax_kernel(float* __restrict__ out) {
    const int row = blockIdx.x;
    float* p = out + (long)row * 10000;
    const int tid = threadIdx.x;
    __shared__ float red[256];

    if ((row & 63) == 0) {
        float lse = logf(expf(1.0f) + 9999.0f);
        for (int v = tid; v < 10000; v += 256) p[v] = (v == 0 ? 1.0f : 0.0f) - lse;
        return;
    }

    float vals[40];
    float m = -3.402823466e38f;
#pragma unroll
    for (int i = 0; i < 40; ++i) {
        int v = tid + (i << 8);
        vals[i] = (v < 10000) ? p[v] : -3.402823466e38f;
        m = fmaxf(m, vals[i]);
    }
    red[tid] = m; __syncthreads();
    for (int s2 = 128; s2; s2 >>= 1) { if (tid < s2) red[tid] = fmaxf(red[tid], red[tid + s2]); __syncthreads(); }
    m = red[0]; __syncthreads();

    float sum = 0.f;
#pragma unroll
    for (int i = 0; i < 40; ++i) {
        int v = tid + (i << 8);
        if (v < 10000) sum += expf(vals[i] - m);
    }
    red[tid] = sum; __syncthreads();
    for (int s2 = 128; s2; s2 >>= 1) { if (tid < s2) red[tid] += red[tid + s2]; __syncthreads(); }
    float lse = m + logf(red[0]);

#pragma unroll
    for (int i = 0; i < 40; ++i) {
        int v = tid + (i << 8);
        if (v < 10000) p[v] = vals[i] - lse;
    }
}

// ---------------------------------------------------------------------------
extern "C" void kernel_launch(void* const* d_in, const int* in_sizes, int n_in,
                              void* d_out, int out_size, void* d_ws, size_t ws_size,
                              hipStream_t stream)
{
    const int*   inp      = (const int*)d_in[0];
    const float* emb_tab  = (const float*)d_in[1];
    const float* eWih_f   = (const float*)d_in[2];
    const float* eWhh_f   = (const float*)d_in[3];
    const float* ebih_f   = (const float*)d_in[4];
    const float* ebhh_f   = (const float*)d_in[5];
    const float* eWih_b   = (const float*)d_in[6];
    const float* eWhh_b   = (const float*)d_in[7];
    const float* ebih_b   = (const float*)d_in[8];
    const float* ebhh_b   = (const float*)d_in[9];
    const float* fc_W     = (const float*)d_in[10];
    const float* fc_b     = (const float*)d_in[11];
    const float* attn_W   = (const float*)d_in[12];
    const float* attn_b   = (const float*)d_in[13];
    const float* dWih     = (const float*)d_in[14];
    const float* dWhh     = (const float*)d_in[15];
    const float* dbih     = (const float*)d_in[16];
    const float* dbhh     = (const float*)d_in[17];
    const float* out_W    = (const float*)d_in[18];
    const float* out_b    = (const float*)d_in[19];

    float* ws = (float*)d_ws;
    float* enc_out = ws;                    // 4,194,304  (B*S*512)
    float* enc_att = enc_out + 4194304;     // 2,097,152  (B*S*256)
    float* hf      = enc_att + 2097152;     // 32768
    float* hb      = hf + 32768;            // 32768
    float* hdec    = hb + 32768;            // 2 * 32768
    float* feat    = hdec + 65536;          // 2 * 131072 (ping-pong)
    unsigned long long* slots = (unsigned long long*)(feat + 262144); // 2*128 u64
    float* out     = (float*)d_out;

    // ---- encoder: one fused launch ----
    enc_loop_kernel<<<128, 512, 0, stream>>>(
        inp, emb_tab, eWih_f, eWhh_f, ebih_f, ebhh_f,
        eWih_b, eWhh_b, ebih_b, ebhh_b, hf, hb, enc_out);
    enc_fc_kernel<<<128, 256, 0, stream>>>(hf, hb, fc_W, fc_b, hdec);

    // enc_att[b,s,a] = enc_out @ attn_W[:,256:768].T + attn_b
    gemm2_kernel<<<dim3(4, 128), 256, 0, stream>>>(
        enc_out, 512, attn_W + 256, 768, attn_b, enc_att, 256, 256, 512);

    // prologue: w(1) from h0 into feat[1]
    attn_kernel<<<128, 256, 0, stream>>>(hdec, attn_W, enc_att, enc_out, feat + 131072);

    // ---- decoder: 2 launches per step ----
    for (int t = 1; t < 64; ++t) {
        float* fb    = feat + (t & 1) * 131072;
        float* fnext = feat + ((t + 1) & 1) * 131072;
        const float* hprev = hdec + ((t - 1) & 1) * 32768;
        float* hcur = hdec + (t & 1) * 32768;
        const unsigned long long* slots_read =
            (t == 1) ? nullptr : slots + ((t - 1) & 1) * 128;
        unsigned long long* slots_cur = slots + (t & 1) * 128;

        dec_gru_kernel<<<128, 256, 0, stream>>>(
            emb_tab, fb, hprev, slots_read, slots_cur,
            dWih, dWhh, dbih, dbhh, hcur);
        mega_kernel<<<378, 256, 0, stream>>>(
            fb, out_W, out_b, out + (long)t * 10000, slots_cur,
            fnext, hcur, attn_W, enc_att, enc_out);
    }

    // ---- final log_softmax (also writes the t=0 one-hot rows) ----
    logsoftmax_kernel<<<8192, 256, 0, stream>>>(out);
}